// Round 1
// baseline (229.509 us; speedup 1.0000x reference)
//
#include <hip/hip_runtime.h>

#define B_SIZE 16384
#define DIM    128
#define NCLS   100

// ---------------- workspace layout (int units) ----------------
// [0, 128)                counts
// [128, 256)              offsets (101 used)
// [256, 256+B)            sorted_idx
// [256+B, 256+2B)         pos_cls
// [256+2B, 256+2B+4096)   partials (float)
#define WS_COUNTS   0
#define WS_OFFSETS  128
#define WS_SORTED   256
#define WS_POSCLS   (256 + B_SIZE)
#define WS_PARTIAL  (256 + 2 * B_SIZE)

#define PAIR_BLOCKS 4096   // 4 waves/block * 4096 = 16384 waves = one per row

__global__ void hist_kernel(const int* __restrict__ target, int* __restrict__ counts) {
    int i = blockIdx.x * blockDim.x + threadIdx.x;
    if (i < B_SIZE) atomicAdd(&counts[target[i]], 1);
}

__global__ void prefix_kernel(const int* __restrict__ counts, int* __restrict__ offsets) {
    if (threadIdx.x == 0 && blockIdx.x == 0) {
        int acc = 0;
        for (int c = 0; c < NCLS; ++c) { offsets[c] = acc; acc += counts[c]; }
        offsets[NCLS] = acc;
    }
}

// One block per class; deterministic stable rank via ballot prefix.
__global__ void rank_scatter_kernel(const int* __restrict__ target,
                                    const int* __restrict__ offsets,
                                    int* __restrict__ sorted_idx,
                                    int* __restrict__ pos_cls) {
    const int c = blockIdx.x;
    __shared__ int base;
    __shared__ int wave_cnt[4];
    if (threadIdx.x == 0) base = offsets[c];
    __syncthreads();

    const int lane = threadIdx.x & 63;
    const int wid  = threadIdx.x >> 6;

    for (int start = 0; start < B_SIZE; start += blockDim.x) {
        int j = start + threadIdx.x;
        bool flag = (j < B_SIZE) && (target[j] == c);
        unsigned long long m = __ballot(flag);
        int wtotal = __popcll(m);
        unsigned long long below = (lane == 0) ? 0ull : (m << (64 - lane));
        int prefix = __popcll(below);
        if (lane == 0) wave_cnt[wid] = wtotal;
        __syncthreads();
        int woff = 0;
        #pragma unroll
        for (int w = 0; w < 4; ++w) if (w < wid) woff += wave_cnt[w];
        int total = wave_cnt[0] + wave_cnt[1] + wave_cnt[2] + wave_cnt[3];
        if (flag) {
            int pos = base + woff + prefix;
            sorted_idx[pos] = j;
            pos_cls[pos] = c;
        }
        __syncthreads();
        if (threadIdx.x == 0) base += total;
        __syncthreads();
    }
}

// One wave per sorted position p: distances to all q > p in same class.
__global__ void pair_kernel(const float* __restrict__ x,
                            const int* __restrict__ sorted_idx,
                            const int* __restrict__ offsets,
                            const int* __restrict__ pos_cls,
                            float* __restrict__ partials) {
    const int lane = threadIdx.x & 63;
    const int wid  = threadIdx.x >> 6;
    const int p    = blockIdx.x * 4 + wid;   // 4 waves per block

    float acc = 0.0f;
    if (p < B_SIZE) {
        const int c   = pos_cls[p];
        const int end = offsets[c + 1];
        const int ia  = sorted_idx[p];
        const float2 a = reinterpret_cast<const float2*>(x + (size_t)ia * DIM)[lane];

        for (int q = p + 1; q < end; ++q) {
            const int ib = sorted_idx[q];
            const float2 b = reinterpret_cast<const float2*>(x + (size_t)ib * DIM)[lane];
            float d0 = a.x - b.x;
            float d1 = a.y - b.y;
            float s = d0 * d0 + d1 * d1;
            #pragma unroll
            for (int off = 32; off > 0; off >>= 1)
                s += __shfl_xor(s, off, 64);
            acc += sqrtf(s);   // all lanes hold identical s after full butterfly
        }
    }

    __shared__ float wsum[4];
    if (lane == 0) wsum[wid] = acc;
    __syncthreads();
    if (threadIdx.x == 0)
        partials[blockIdx.x] = wsum[0] + wsum[1] + wsum[2] + wsum[3];
}

__global__ void reduce_kernel(const float* __restrict__ partials, float* __restrict__ out) {
    __shared__ float sm[256];
    float acc = 0.0f;
    for (int i = threadIdx.x; i < PAIR_BLOCKS; i += 256) acc += partials[i];
    sm[threadIdx.x] = acc;
    __syncthreads();
    for (int s = 128; s > 0; s >>= 1) {
        if (threadIdx.x < s) sm[threadIdx.x] += sm[threadIdx.x + s];
        __syncthreads();
    }
    if (threadIdx.x == 0) out[0] = sm[0] / (float)B_SIZE;
}

extern "C" void kernel_launch(void* const* d_in, const int* in_sizes, int n_in,
                              void* d_out, int out_size, void* d_ws, size_t ws_size,
                              hipStream_t stream) {
    const float* x      = (const float*)d_in[0];
    const int*   target = (const int*)d_in[1];
    float*       out    = (float*)d_out;
    int*         ws     = (int*)d_ws;

    int*   counts   = ws + WS_COUNTS;
    int*   offsets  = ws + WS_OFFSETS;
    int*   sorted   = ws + WS_SORTED;
    int*   poscls   = ws + WS_POSCLS;
    float* partials = (float*)(ws + WS_PARTIAL);

    hipMemsetAsync(counts, 0, 128 * sizeof(int), stream);
    hist_kernel<<<(B_SIZE + 255) / 256, 256, 0, stream>>>(target, counts);
    prefix_kernel<<<1, 64, 0, stream>>>(counts, offsets);
    rank_scatter_kernel<<<NCLS, 256, 0, stream>>>(target, offsets, sorted, poscls);
    pair_kernel<<<PAIR_BLOCKS, 256, 0, stream>>>(x, sorted, offsets, poscls, partials);
    reduce_kernel<<<1, 256, 0, stream>>>(partials, out);
}

// Round 2
// 52.008 us; speedup vs baseline: 4.4130x; 4.4130x over previous
//
#include <hip/hip_runtime.h>

#define B_SIZE 16384
#define DIM    128
#define NCLS   100
#define NSEG   64            // 64 segments x 256 elements = 16384
#define SEGSZ  256
#define TS     32            // pair-tile side
#define LSTR   132           // LDS row stride in floats (pad 128 -> 132)
#define MAXTILES 131329
#define PAIR_GRID 2048
#define NORM_GRID 2048       // 8 rows per block

// ---------------- workspace layout (int units) ----------------
#define WS_OFFSETS  0                    // 101 (pad 128)
#define WS_SEGHIST  128                  // 64*100 = 6400
#define WS_SEGBASE  (128 + 6400)         // 6400
#define WS_SORTED   (WS_SEGBASE + 6400)  // 16384
#define WS_NORMS    (WS_SORTED + 16384)  // 16384 floats
#define WS_NTILES   (WS_NORMS + 16384)   // 1
#define WS_TILES    (WS_NTILES + 63)     // MAXTILES (aligned-ish)
#define WS_PARTIAL  (WS_TILES + MAXTILES)// PAIR_GRID floats

// 1) per-segment class histogram (deterministic: counts only)
__global__ void seghist_kernel(const int* __restrict__ target, int* __restrict__ seg_hist) {
    __shared__ int h[NCLS];
    if (threadIdx.x < NCLS) h[threadIdx.x] = 0;
    __syncthreads();
    int i = blockIdx.x * SEGSZ + threadIdx.x;
    atomicAdd(&h[target[i]], 1);
    __syncthreads();
    if (threadIdx.x < NCLS) seg_hist[blockIdx.x * NCLS + threadIdx.x] = h[threadIdx.x];
}

// 2) single-block scan: class offsets, per-segment bases, tile list
__global__ void scan_kernel(const int* __restrict__ seg_hist,
                            int* __restrict__ offsets,
                            int* __restrict__ seg_base,
                            int* __restrict__ tiles,
                            int* __restrict__ ntiles) {
    __shared__ int tot[NCLS], cls_off[NCLS + 1], tcnt[NCLS], tile_off[NCLS + 1];
    const int c = threadIdx.x;
    if (c < NCLS) {
        int s = 0;
        for (int g = 0; g < NSEG; ++g) s += seg_hist[g * NCLS + c];
        tot[c] = s;
    }
    __syncthreads();
    if (threadIdx.x == 0) {
        int a = 0;
        for (int k = 0; k < NCLS; ++k) { cls_off[k] = a; a += tot[k]; }
        cls_off[NCLS] = a;
    }
    __syncthreads();
    if (c < NCLS) {
        offsets[c] = cls_off[c];
        int a = cls_off[c];
        for (int g = 0; g < NSEG; ++g) { seg_base[g * NCLS + c] = a; a += seg_hist[g * NCLS + c]; }
        int T = (tot[c] + TS - 1) / TS;
        tcnt[c] = T * (T + 1) / 2;
    }
    __syncthreads();
    if (threadIdx.x == 0) {
        offsets[NCLS] = cls_off[NCLS];
        int a = 0;
        for (int k = 0; k < NCLS; ++k) { tile_off[k] = a; a += tcnt[k]; }
        tile_off[NCLS] = a;
        *ntiles = (a > MAXTILES) ? MAXTILES : a;
    }
    __syncthreads();
    if (c < NCLS) {
        int o = tile_off[c];
        int T = (tot[c] + TS - 1) / TS;
        for (int ti = 0; ti < T; ++ti)
            for (int tj = ti; tj < T; ++tj) {
                if (o < MAXTILES) tiles[o] = (c << 18) | (ti << 9) | tj;
                ++o;
            }
    }
}

// 3) stable in-segment rank + scatter (deterministic)
__global__ void scatter_kernel(const int* __restrict__ target,
                               const int* __restrict__ seg_base,
                               int* __restrict__ sorted_idx) {
    __shared__ int tloc[SEGSZ];
    __shared__ int base_s[NCLS];
    const int seg = blockIdx.x;
    const int i = seg * SEGSZ + threadIdx.x;
    const int c = target[i];
    tloc[threadIdx.x] = c;
    if (threadIdx.x < NCLS) base_s[threadIdx.x] = seg_base[seg * NCLS + threadIdx.x];
    __syncthreads();
    int r = 0;
    for (int j = 0; j < (int)threadIdx.x; ++j) r += (tloc[j] == c);
    sorted_idx[base_s[c] + r] = i;
}

// 4) squared norms in sorted order; 8 rows / block, 32 lanes / row
__global__ void norm_kernel(const float* __restrict__ x,
                            const int* __restrict__ sorted_idx,
                            float* __restrict__ normS) {
    const int pos = blockIdx.x * 8 + (threadIdx.x >> 5);
    const int col = threadIdx.x & 31;
    const int idx = sorted_idx[pos];
    const float4 v = reinterpret_cast<const float4*>(x + (size_t)idx * DIM)[col];
    float s = v.x * v.x + v.y * v.y + v.z * v.z + v.w * v.w;
    #pragma unroll
    for (int off = 16; off > 0; off >>= 1) s += __shfl_xor(s, off, 64);
    if (col == 0) normS[pos] = s;
}

// 5) persistent tile kernel: 32x32 pair tiles, 2x2 register tiling, dot trick
__global__ __launch_bounds__(256) void pair_tiles_kernel(
        const float* __restrict__ x,
        const int* __restrict__ sorted_idx,
        const int* __restrict__ offsets,
        const float* __restrict__ normS,
        const int* __restrict__ tiles,
        const int* __restrict__ ntiles_p,
        float* __restrict__ partials) {
    __shared__ __align__(16) float A[TS * LSTR];
    __shared__ __align__(16) float Bm[TS * LSTR];
    __shared__ float nA[TS], nB[TS];
    __shared__ float red[256];

    const int nt = *ntiles_p;
    const int tx = threadIdx.x & 15;
    const int ty = threadIdx.x >> 4;
    float acc = 0.0f;

    for (int t = blockIdx.x; t < nt; t += gridDim.x) {
        const int e  = tiles[t];
        const int c  = e >> 18;
        const int ti = (e >> 9) & 511;
        const int tj = e & 511;
        const int beg = offsets[c];
        const int end = offsets[c + 1];
        const int pbase = beg + ti * TS;
        const int qbase = beg + tj * TS;

        __syncthreads();   // previous tile's LDS reads done
        // stage 64 rows (zero-fill past class end)
        for (int i = threadIdx.x; i < 64 * 32; i += 256) {
            const int row = i >> 5, col = i & 31;
            const int pos = (row < TS) ? (pbase + row) : (qbase + row - TS);
            float4 v = make_float4(0.f, 0.f, 0.f, 0.f);
            if (pos < end) {
                const int idx = sorted_idx[pos];
                v = reinterpret_cast<const float4*>(x + (size_t)idx * DIM)[col];
            }
            float* dst = (row < TS) ? &A[row * LSTR] : &Bm[(row - TS) * LSTR];
            reinterpret_cast<float4*>(dst)[col] = v;
        }
        if (threadIdx.x < 64) {
            const int r = threadIdx.x;
            const int pos = (r < TS) ? (pbase + r) : (qbase + r - TS);
            const float nv = (pos < end) ? normS[pos] : 0.f;
            if (r < TS) nA[r] = nv; else nB[r - TS] = nv;
        }
        __syncthreads();

        float d00 = 0.f, d01 = 0.f, d10 = 0.f, d11 = 0.f;
        #pragma unroll 4
        for (int k = 0; k < 32; ++k) {
            const float4 a0 = reinterpret_cast<const float4*>(&A[ty * LSTR])[k];
            const float4 a1 = reinterpret_cast<const float4*>(&A[(ty + 16) * LSTR])[k];
            const float4 b0 = reinterpret_cast<const float4*>(&Bm[tx * LSTR])[k];
            const float4 b1 = reinterpret_cast<const float4*>(&Bm[(tx + 16) * LSTR])[k];
            d00 += a0.x * b0.x + a0.y * b0.y + a0.z * b0.z + a0.w * b0.w;
            d01 += a0.x * b1.x + a0.y * b1.y + a0.z * b1.z + a0.w * b1.w;
            d10 += a1.x * b0.x + a1.y * b0.y + a1.z * b0.z + a1.w * b0.w;
            d11 += a1.x * b1.x + a1.y * b1.y + a1.z * b1.z + a1.w * b1.w;
        }

        const bool diag = (ti == tj);
        #pragma unroll
        for (int s = 0; s < 4; ++s) {
            const int py = ty + ((s & 2) ? 16 : 0);
            const int qx = tx + ((s & 1) ? 16 : 0);
            const float dot = (s == 0) ? d00 : (s == 1) ? d01 : (s == 2) ? d10 : d11;
            const bool valid = (pbase + py < end) && (qbase + qx < end) &&
                               (!diag || (py < qx));
            if (valid) {
                const float sq = nA[py] + nB[qx] - 2.0f * dot;
                acc += sqrtf(fmaxf(sq, 0.0f));
            }
        }
    }

    __syncthreads();
    red[threadIdx.x] = acc;
    __syncthreads();
    for (int s = 128; s > 0; s >>= 1) {
        if (threadIdx.x < s) red[threadIdx.x] += red[threadIdx.x + s];
        __syncthreads();
    }
    if (threadIdx.x == 0) partials[blockIdx.x] = red[0];
}

__global__ void reduce_kernel(const float* __restrict__ partials, float* __restrict__ out) {
    __shared__ float sm[256];
    float acc = 0.0f;
    for (int i = threadIdx.x; i < PAIR_GRID; i += 256) acc += partials[i];
    sm[threadIdx.x] = acc;
    __syncthreads();
    for (int s = 128; s > 0; s >>= 1) {
        if (threadIdx.x < s) sm[threadIdx.x] += sm[threadIdx.x + s];
        __syncthreads();
    }
    if (threadIdx.x == 0) out[0] = sm[0] / (float)B_SIZE;
}

extern "C" void kernel_launch(void* const* d_in, const int* in_sizes, int n_in,
                              void* d_out, int out_size, void* d_ws, size_t ws_size,
                              hipStream_t stream) {
    const float* x      = (const float*)d_in[0];
    const int*   target = (const int*)d_in[1];
    float*       out    = (float*)d_out;
    int*         ws     = (int*)d_ws;

    int*   offsets  = ws + WS_OFFSETS;
    int*   seg_hist = ws + WS_SEGHIST;
    int*   seg_base = ws + WS_SEGBASE;
    int*   sorted   = ws + WS_SORTED;
    float* normS    = (float*)(ws + WS_NORMS);
    int*   ntiles   = ws + WS_NTILES;
    int*   tiles    = ws + WS_TILES;
    float* partials = (float*)(ws + WS_PARTIAL);

    seghist_kernel<<<NSEG, SEGSZ, 0, stream>>>(target, seg_hist);
    scan_kernel<<<1, 128, 0, stream>>>(seg_hist, offsets, seg_base, tiles, ntiles);
    scatter_kernel<<<NSEG, SEGSZ, 0, stream>>>(target, seg_base, sorted);
    norm_kernel<<<NORM_GRID, 256, 0, stream>>>(x, sorted, normS);
    pair_tiles_kernel<<<PAIR_GRID, 256, 0, stream>>>(x, sorted, offsets, normS,
                                                     tiles, ntiles, partials);
    reduce_kernel<<<1, 256, 0, stream>>>(partials, out);
}